// Round 1
// baseline (1134.388 us; speedup 1.0000x reference)
//
#include <hip/hip_runtime.h>
#include <hip/hip_bf16.h>

#define NT_ 10000
#define B_  128
#define S_  500

// ---------------------------------------------------------------------------
// Kernel A: per-topic precompute
//   topicAct[t][u]  = emb_topic[t] @ W_in[0:128]          (a's topic part)
//   topicGate[t][u] = emb_topic[t] @ W_gate[256:384]      (gamma's e part)
// last block (blk==1250): respAct[r][u] = emb_resps[r] @ W_in[128:256]
// ---------------------------------------------------------------------------
__global__ __launch_bounds__(128) void prep_topic(
    const float* __restrict__ emb_topic,
    const float* __restrict__ emb_resps,
    const float* __restrict__ W_in,
    const float* __restrict__ W_gate,
    float* __restrict__ topicAct,
    float* __restrict__ topicGate,
    float* __restrict__ respAct)
{
    const int u = threadIdx.x;
    __shared__ float e[8][128];
    const int blk = blockIdx.x;

    if (blk == NT_ / 8) {
        e[0][u] = emb_resps[u];
        e[1][u] = emb_resps[128 + u];
        __syncthreads();
        float a0 = 0.f, a1 = 0.f;
        for (int k = 0; k < 128; ++k) {
            float wv = W_in[(128 + k) * 128 + u];
            a0 += e[0][k] * wv;
            a1 += e[1][k] * wv;
        }
        respAct[u]       = a0;
        respAct[128 + u] = a1;
        return;
    }

    const int t0 = blk * 8;
    #pragma unroll
    for (int j = 0; j < 8; ++j) e[j][u] = emb_topic[(t0 + j) * 128 + u];
    __syncthreads();

    float accA[8], accG[8];
    #pragma unroll
    for (int j = 0; j < 8; ++j) { accA[j] = 0.f; accG[j] = 0.f; }

    for (int k = 0; k < 128; ++k) {
        float wa = W_in[k * 128 + u];
        float wg = W_gate[(256 + k) * 128 + u];
        #pragma unroll
        for (int j = 0; j < 8; ++j) {
            accA[j] += e[j][k] * wa;
            accG[j] += e[j][k] * wg;
        }
    }
    #pragma unroll
    for (int j = 0; j < 8; ++j) {
        topicAct [(t0 + j) * 128 + u] = accA[j];
        topicGate[(t0 + j) * 128 + u] = accG[j];
    }
}

// ---------------------------------------------------------------------------
// Kernel B: per-(topic,resp) streams.
//   a = relu(topicAct[t] + respAct[r] + b_in)
//   streams[(t*2+r)*512 + mat*128 + u]:
//     mat0: a @ W_time[1:129]    mat1: a @ W_att[1:129]
//     mat2: a @ W_hint[1:129]    mat3: a @ W_gate[128:256] + topicGate[t]
// 8 topics x 2 resps = 16 rows per block.
// ---------------------------------------------------------------------------
__global__ __launch_bounds__(128) void prep_streams(
    const float* __restrict__ topicAct,
    const float* __restrict__ topicGate,
    const float* __restrict__ respAct,
    const float* __restrict__ b_in,
    const float* __restrict__ W_time,
    const float* __restrict__ W_att,
    const float* __restrict__ W_hint,
    const float* __restrict__ W_gate,
    float* __restrict__ streams)
{
    const int u  = threadIdx.x;
    const int t0 = blockIdx.x * 8;
    __shared__ float a_lds[16][128];

    const float bi = b_in[u];
    const float r0 = respAct[u];
    const float r1 = respAct[128 + u];
    #pragma unroll
    for (int j = 0; j < 8; ++j) {
        float ta = topicAct[(t0 + j) * 128 + u];
        a_lds[j * 2 + 0][u] = fmaxf(ta + r0 + bi, 0.f);
        a_lds[j * 2 + 1][u] = fmaxf(ta + r1 + bi, 0.f);
    }
    __syncthreads();

    const float* Wm[4] = { W_time + 128 + u, W_att + 128 + u,
                           W_hint + 128 + u, W_gate + 128 * 128 + u };

    for (int mat = 0; mat < 4; ++mat) {
        const float* Wp = Wm[mat];
        float acc[16];
        #pragma unroll
        for (int r = 0; r < 16; ++r) acc[r] = 0.f;
        for (int k = 0; k < 128; ++k) {
            float wv = Wp[(size_t)k * 128];
            #pragma unroll
            for (int r = 0; r < 16; ++r) acc[r] += a_lds[r][k] * wv;
        }
        #pragma unroll
        for (int r = 0; r < 16; ++r) {
            float v = acc[r];
            int   t = t0 + (r >> 1);
            if (mat == 3) v += topicGate[t * 128 + u];
            streams[((size_t)t * 2 + (r & 1)) * 512 + mat * 128 + u] = v;
        }
    }
}

// ---------------------------------------------------------------------------
// Kernel C: the 500-step recurrence. 1 block per batch row, 512 threads:
//   u = tid & 127 (output unit), q = tid >> 7 (k-slice of 32).
// Weights register-resident: 5 x 32 f32 per thread. H register-resident:
// thread (q,u) holds H[q*8+j][u], j<8.
// ---------------------------------------------------------------------------
__device__ __forceinline__ float waveRed(float v) {
    #pragma unroll
    for (int o = 32; o > 0; o >>= 1) v += __shfl_down(v, o, 64);
    return v;
}
__device__ __forceinline__ float sigmoidf_(float x) {
    return 1.f / (1.f + __expf(-x));
}
__device__ __forceinline__ float tanhf_(float x) {
    float e = __expf(2.f * x);
    return 1.f - 2.f / (e + 1.f);
}

__global__ __launch_bounds__(512, 2) void recurrent(
    const int*   __restrict__ topics, const int* __restrict__ resps,
    const float* __restrict__ tf_, const float* __restrict__ af_,
    const float* __restrict__ hf_, const int* __restrict__ masks,
    const float* __restrict__ q_matrix, const float* __restrict__ init_h,
    const float* __restrict__ W_out,  const float* __restrict__ b_out,
    const float* __restrict__ W_time, const float* __restrict__ b_time,
    const float* __restrict__ W_att,  const float* __restrict__ b_att,
    const float* __restrict__ W_hint, const float* __restrict__ b_hint,
    const float* __restrict__ W_cap,  const float* __restrict__ b_cap,
    const float* __restrict__ w_lg,
    const float* __restrict__ W_gate, const float* __restrict__ b_gate,
    const float* __restrict__ streams,
    float* __restrict__ out)
{
    const int tid = threadIdx.x;
    const int u   = tid & 127;
    const int q   = tid >> 7;
    const int b   = blockIdx.x;

    __shared__ float w_lds[2][32];            // double-buffered
    __shared__ __align__(16) float ht_lds[128];
    __shared__ float part_ht[512];
    __shared__ float part5[5 * 512];
    __shared__ float gamma_lds[128], lg_lds[128];
    __shared__ float red_s[2], red_l[2];

    // ---- register-resident weights (k-slice q*32 .. q*32+31) ----
    float Wout_r[32], Wt_r[32], Wa_r[32], Wh_r[32], Wg_r[32];
    const int kb = q * 32;
    #pragma unroll
    for (int kk = 0; kk < 32; ++kk) {
        Wout_r[kk] = W_out [(kb + kk) * 128 + u];
        Wt_r[kk]   = W_time[(129 + kb + kk) * 128 + u];
        Wa_r[kk]   = W_att [(129 + kb + kk) * 128 + u];
        Wh_r[kk]   = W_hint[(129 + kb + kk) * 128 + u];
        Wg_r[kk]   = W_gate[(kb + kk) * 128 + u];
    }
    float Hreg[8];
    #pragma unroll
    for (int j = 0; j < 8; ++j) Hreg[j] = init_h[(q * 8 + j) * 128 + u];

    // ---- epilogue constants (only q==0 threads use them) ----
    float bo = 0, bt = 0, ba = 0, bh = 0, bg = 0, wt0 = 0, wa0 = 0, wh0 = 0;
    float wc0=0,wc1=0,wc2=0,wc3=0,wc4=0,wc5=0,wc6=0,wc7=0;
    float bcap = 0, wl0 = 0, wl1 = 0, wl2 = 0;
    if (q == 0) {
        bo = b_out[u]; bt = b_time[u]; ba = b_att[u]; bh = b_hint[u]; bg = b_gate[u];
        wt0 = W_time[u]; wa0 = W_att[u]; wh0 = W_hint[u];
        wc0=W_cap[0]; wc1=W_cap[1]; wc2=W_cap[2]; wc3=W_cap[3];
        wc4=W_cap[4]; wc5=W_cap[5]; wc6=W_cap[6]; wc7=W_cap[7];
        bcap = b_cap[0];
        wl0 = w_lg[0]; wl1 = w_lg[1]; wl2 = w_lg[2];
    }

    const int base = b * S_;
    float* out_imp = out + B_ * (S_ - 1);

    #pragma unroll 1
    for (int s = 0; s < S_; ++s) {
        const int   buf   = s & 1;
        const int   topic = topics[base + s];
        const int   resp  = resps [base + s];
        const int   mask  = masks [base + s];
        const float tf = tf_[base + s], af = af_[base + s], hf = hf_[base + s];

        if (tid < 32) w_lds[buf][tid] = q_matrix[topic * 32 + tid];

        float sv0 = 0, sv1 = 0, sv2 = 0, sv3 = 0;
        if (q == 0) {
            const float* sp = streams + ((size_t)topic * 2 + resp) * 512 + u;
            sv0 = sp[0]; sv1 = sp[128]; sv2 = sp[256]; sv3 = sp[384];
        }
        __syncthreads();                                      // B1

        // h_tilde partials over this thread's m-slice
        float p = 0.f;
        #pragma unroll
        for (int j = 0; j < 8; ++j) p += w_lds[buf][q * 8 + j] * Hreg[j];
        part_ht[q * 128 + u] = p;
        __syncthreads();                                      // B2

        if (q == 0)
            ht_lds[u] = part_ht[u] + part_ht[128 + u] +
                        part_ht[256 + u] + part_ht[384 + u];
        __syncthreads();                                      // B3

        // five dot products over register weights, k-slice from LDS
        float a0 = 0, a1 = 0, a2 = 0, a3 = 0, a4 = 0;
        #pragma unroll
        for (int c = 0; c < 8; ++c) {
            float4 h4 = *(const float4*)&ht_lds[q * 32 + c * 4];
            a0 += Wout_r[c*4+0]*h4.x + Wout_r[c*4+1]*h4.y + Wout_r[c*4+2]*h4.z + Wout_r[c*4+3]*h4.w;
            a1 += Wt_r [c*4+0]*h4.x + Wt_r [c*4+1]*h4.y + Wt_r [c*4+2]*h4.z + Wt_r [c*4+3]*h4.w;
            a2 += Wa_r [c*4+0]*h4.x + Wa_r [c*4+1]*h4.y + Wa_r [c*4+2]*h4.z + Wa_r [c*4+3]*h4.w;
            a3 += Wh_r [c*4+0]*h4.x + Wh_r [c*4+1]*h4.y + Wh_r [c*4+2]*h4.z + Wh_r [c*4+3]*h4.w;
            a4 += Wg_r [c*4+0]*h4.x + Wg_r [c*4+1]*h4.y + Wg_r [c*4+2]*h4.z + Wg_r [c*4+3]*h4.w;
        }
        part5[0 * 512 + tid] = a0;
        part5[1 * 512 + tid] = a1;
        part5[2 * 512 + tid] = a2;
        part5[3 * 512 + tid] = a3;
        part5[4 * 512 + tid] = a4;
        __syncthreads();                                      // B4

        if (q == 0) {
            float z0 = part5[0*512+u] + part5[0*512+128+u] + part5[0*512+256+u] + part5[0*512+384+u];
            float z1 = part5[1*512+u] + part5[1*512+128+u] + part5[1*512+256+u] + part5[1*512+384+u];
            float z2 = part5[2*512+u] + part5[2*512+128+u] + part5[2*512+256+u] + part5[2*512+384+u];
            float z3 = part5[3*512+u] + part5[3*512+128+u] + part5[3*512+256+u] + part5[3*512+384+u];
            float z4 = part5[4*512+u] + part5[4*512+128+u] + part5[4*512+256+u] + part5[4*512+384+u];

            float sig = sigmoidf_(z0 + bo);
            float gt  = tanhf_(z1 + sv0 + tf * wt0 + bt) * tf;
            float ga  = tanhf_(z2 + sv1 + af * wa0 + ba) * af;
            float gh  = tanhf_(z3 + sv2 + hf * wh0 + bh) * hf;

            float capin = wc0*tf + wc1*af + wc2*hf + wc3*(tf*af) + wc4*(tf*hf)
                        + wc5*(af*hf) + wc6*(tf*af*hf) + wc7 + bcap;
            float cap = sigmoidf_(capin);
            float lg  = cap * fmaxf(wl0 * gt + wl1 * ga + wl2 * gh, 0.f);
            float gamma = sigmoidf_(z4 + sv3 + bg);

            gamma_lds[u] = gamma;
            lg_lds[u]    = lg;

            float rs = waveRed(sig);
            float rl = waveRed(lg);
            if ((tid & 63) == 0) { red_s[tid >> 6] = rs; red_l[tid >> 6] = rl; }
        }
        __syncthreads();                                      // B5

        if (mask) {
            float gm = gamma_lds[u], lg = lg_lds[u];
            #pragma unroll
            for (int j = 0; j < 8; ++j)
                Hreg[j] = gm * Hreg[j] + w_lds[buf][q * 8 + j] * lg;
        }

        if (tid == 0) {
            float preds = (red_s[0] + red_s[1]) * (1.f / 128.f);
            float imp   = (red_l[0] + red_l[1]) * (1.f / 128.f);
            if (!mask) { preds = 0.f; imp = 0.f; }
            if (s >= 1) out[b * (S_ - 1) + (s - 1)] = preds;
            out_imp[b * S_ + s] = imp;
        }
    }
}

// ---------------------------------------------------------------------------
extern "C" void kernel_launch(void* const* d_in, const int* in_sizes, int n_in,
                              void* d_out, int out_size, void* d_ws, size_t ws_size,
                              hipStream_t stream)
{
    (void)in_sizes; (void)n_in; (void)out_size; (void)ws_size;

    const int*   topics    = (const int*)  d_in[0];
    const int*   resps     = (const int*)  d_in[1];
    const float* tf        = (const float*)d_in[2];
    const float* af        = (const float*)d_in[3];
    const float* hf        = (const float*)d_in[4];
    const int*   masks     = (const int*)  d_in[5];
    /* d_in[6] = training (ignored) */
    const float* emb_topic = (const float*)d_in[7];
    const float* emb_resps = (const float*)d_in[8];
    const float* q_matrix  = (const float*)d_in[9];
    const float* W_in      = (const float*)d_in[10];
    const float* b_in      = (const float*)d_in[11];
    const float* init_h    = (const float*)d_in[12];
    const float* W_out     = (const float*)d_in[13];
    const float* b_out     = (const float*)d_in[14];
    const float* W_time    = (const float*)d_in[15];
    const float* b_time    = (const float*)d_in[16];
    const float* W_att     = (const float*)d_in[17];
    const float* b_att     = (const float*)d_in[18];
    const float* W_hint    = (const float*)d_in[19];
    const float* b_hint    = (const float*)d_in[20];
    const float* W_cap     = (const float*)d_in[21];
    const float* b_cap     = (const float*)d_in[22];
    const float* w_lg      = (const float*)d_in[23];
    const float* W_gate    = (const float*)d_in[24];
    const float* b_gate    = (const float*)d_in[25];

    float* ws        = (float*)d_ws;
    float* topicAct  = ws;                         // 10000*128
    float* topicGate = topicAct + NT_ * 128;       // 10000*128
    float* respAct   = topicGate + NT_ * 128;      // 256
    float* streams   = respAct + 256;              // 10000*2*512

    prep_topic  <<<NT_ / 8 + 1, 128, 0, stream>>>(emb_topic, emb_resps, W_in, W_gate,
                                                  topicAct, topicGate, respAct);
    prep_streams<<<NT_ / 8,     128, 0, stream>>>(topicAct, topicGate, respAct, b_in,
                                                  W_time, W_att, W_hint, W_gate, streams);
    recurrent   <<<B_, 512, 0, stream>>>(topics, resps, tf, af, hf, masks,
                                         q_matrix, init_h,
                                         W_out, b_out, W_time, b_time,
                                         W_att, b_att, W_hint, b_hint,
                                         W_cap, b_cap, w_lg, W_gate, b_gate,
                                         streams, (float*)d_out);
}

// Round 2
// 961.713 us; speedup vs baseline: 1.1795x; 1.1795x over previous
//
#include <hip/hip_runtime.h>
#include <hip/hip_bf16.h>

#define NT_ 10000
#define B_  128
#define S_  500

// ---------------------------------------------------------------------------
// Kernel A: per-topic precompute
//   topicAct[t][u]  = emb_topic[t] @ W_in[0:128]          (a's topic part)
//   topicGate[t][u] = emb_topic[t] @ W_gate[256:384]      (gamma's e part)
// last block (blk==1250): respAct[r][u] = emb_resps[r] @ W_in[128:256]
// ---------------------------------------------------------------------------
__global__ __launch_bounds__(128) void prep_topic(
    const float* __restrict__ emb_topic,
    const float* __restrict__ emb_resps,
    const float* __restrict__ W_in,
    const float* __restrict__ W_gate,
    float* __restrict__ topicAct,
    float* __restrict__ topicGate,
    float* __restrict__ respAct)
{
    const int u = threadIdx.x;
    __shared__ float e[8][128];
    const int blk = blockIdx.x;

    if (blk == NT_ / 8) {
        e[0][u] = emb_resps[u];
        e[1][u] = emb_resps[128 + u];
        __syncthreads();
        float a0 = 0.f, a1 = 0.f;
        for (int k = 0; k < 128; ++k) {
            float wv = W_in[(128 + k) * 128 + u];
            a0 += e[0][k] * wv;
            a1 += e[1][k] * wv;
        }
        respAct[u]       = a0;
        respAct[128 + u] = a1;
        return;
    }

    const int t0 = blk * 8;
    #pragma unroll
    for (int j = 0; j < 8; ++j) e[j][u] = emb_topic[(t0 + j) * 128 + u];
    __syncthreads();

    float accA[8], accG[8];
    #pragma unroll
    for (int j = 0; j < 8; ++j) { accA[j] = 0.f; accG[j] = 0.f; }

    for (int k = 0; k < 128; ++k) {
        float wa = W_in[k * 128 + u];
        float wg = W_gate[(256 + k) * 128 + u];
        #pragma unroll
        for (int j = 0; j < 8; ++j) {
            accA[j] += e[j][k] * wa;
            accG[j] += e[j][k] * wg;
        }
    }
    #pragma unroll
    for (int j = 0; j < 8; ++j) {
        topicAct [(t0 + j) * 128 + u] = accA[j];
        topicGate[(t0 + j) * 128 + u] = accG[j];
    }
}

// ---------------------------------------------------------------------------
// Kernel B: per-(topic,resp) streams.
//   a = relu(topicAct[t] + respAct[r] + b_in)
//   streams[(t*2+r)*512 + mat*128 + u]:
//     mat0: a @ W_time[1:129]    mat1: a @ W_att[1:129]
//     mat2: a @ W_hint[1:129]    mat3: a @ W_gate[128:256] + topicGate[t]
// ---------------------------------------------------------------------------
__global__ __launch_bounds__(128) void prep_streams(
    const float* __restrict__ topicAct,
    const float* __restrict__ topicGate,
    const float* __restrict__ respAct,
    const float* __restrict__ b_in,
    const float* __restrict__ W_time,
    const float* __restrict__ W_att,
    const float* __restrict__ W_hint,
    const float* __restrict__ W_gate,
    float* __restrict__ streams)
{
    const int u  = threadIdx.x;
    const int t0 = blockIdx.x * 8;
    __shared__ float a_lds[16][128];

    const float bi = b_in[u];
    const float r0 = respAct[u];
    const float r1 = respAct[128 + u];
    #pragma unroll
    for (int j = 0; j < 8; ++j) {
        float ta = topicAct[(t0 + j) * 128 + u];
        a_lds[j * 2 + 0][u] = fmaxf(ta + r0 + bi, 0.f);
        a_lds[j * 2 + 1][u] = fmaxf(ta + r1 + bi, 0.f);
    }
    __syncthreads();

    const float* Wm[4] = { W_time + 128 + u, W_att + 128 + u,
                           W_hint + 128 + u, W_gate + 128 * 128 + u };

    for (int mat = 0; mat < 4; ++mat) {
        const float* Wp = Wm[mat];
        float acc[16];
        #pragma unroll
        for (int r = 0; r < 16; ++r) acc[r] = 0.f;
        for (int k = 0; k < 128; ++k) {
            float wv = Wp[(size_t)k * 128];
            #pragma unroll
            for (int r = 0; r < 16; ++r) acc[r] += a_lds[r][k] * wv;
        }
        #pragma unroll
        for (int r = 0; r < 16; ++r) {
            float v = acc[r];
            int   t = t0 + (r >> 1);
            if (mat == 3) v += topicGate[t * 128 + u];
            streams[((size_t)t * 2 + (r & 1)) * 512 + mat * 128 + u] = v;
        }
    }
}

// ---------------------------------------------------------------------------
// Kernel C: 500-step recurrence. 1 block/batch row, 512 threads.
//   u = tid>>2 (output unit 0..127), q = tid&3 (k-slice of 32).
// The 4 q-lanes of a u sit in ADJACENT lanes of one wave -> all cross-q
// reductions are shfl_xor(1)/shfl_xor(2); one barrier/step (ht broadcast).
// Weights register-resident (160 f32/thread), H register-resident (8/thread,
// m-sliced). Epilogue redundant on all 4 q-lanes. All per-step globals
// prefetched 1-3 steps ahead. Outputs: wave butterfly + deferred write.
// ---------------------------------------------------------------------------
__device__ __forceinline__ float sigmoidf_(float x) {
    return 1.f / (1.f + __expf(-x));
}
__device__ __forceinline__ float tanhf_(float x) {
    float e = __expf(2.f * x);
    return 1.f - 2.f / (e + 1.f);
}

__global__ __launch_bounds__(512) __attribute__((amdgpu_waves_per_eu(2, 2)))
void recurrent(
    const int*   __restrict__ topics, const int* __restrict__ resps,
    const float* __restrict__ tf_, const float* __restrict__ af_,
    const float* __restrict__ hf_, const int* __restrict__ masks,
    const float* __restrict__ q_matrix, const float* __restrict__ init_h,
    const float* __restrict__ W_out,  const float* __restrict__ b_out,
    const float* __restrict__ W_time, const float* __restrict__ b_time,
    const float* __restrict__ W_att,  const float* __restrict__ b_att,
    const float* __restrict__ W_hint, const float* __restrict__ b_hint,
    const float* __restrict__ W_cap,  const float* __restrict__ b_cap,
    const float* __restrict__ w_lg,
    const float* __restrict__ W_gate, const float* __restrict__ b_gate,
    const float* __restrict__ streams,
    float* __restrict__ out)
{
    const int tid = threadIdx.x;
    const int u   = tid >> 2;     // 0..127
    const int q   = tid & 3;      // 0..3
    const int wv  = tid >> 6;     // wave 0..7
    const int b   = blockIdx.x;

    __shared__ float w_lds[2][32];
    __shared__ __align__(16) float ht_lds[2][144];   // 4 slices of 32, +4 pad each
    __shared__ float red[2][8][2];

    // ---- register-resident weights: k-slice [q*32, q*32+32) ----
    float Wo[32], Wt[32], Wa[32], Wh[32], Wg[32];
    const int kb = q * 32;
    #pragma unroll
    for (int kk = 0; kk < 32; ++kk) {
        Wo[kk] = W_out [(kb + kk) * 128 + u];
        Wt[kk] = W_time[(129 + kb + kk) * 128 + u];
        Wa[kk] = W_att [(129 + kb + kk) * 128 + u];
        Wh[kk] = W_hint[(129 + kb + kk) * 128 + u];
        Wg[kk] = W_gate[(kb + kk) * 128 + u];
    }
    // H[m][u] for m = q*8 .. q*8+7
    float H[8];
    #pragma unroll
    for (int j = 0; j < 8; ++j) H[j] = init_h[(q * 8 + j) * 128 + u];

    // per-u epilogue constants (all lanes — epilogue is redundant over q)
    const float bo = b_out[u], bt = b_time[u], ba = b_att[u], bh = b_hint[u], bg = b_gate[u];
    const float wt0 = W_time[u], wa0 = W_att[u], wh0 = W_hint[u];
    const float wc0 = W_cap[0], wc1 = W_cap[1], wc2 = W_cap[2], wc3 = W_cap[3];
    const float wc4 = W_cap[4], wc5 = W_cap[5], wc6 = W_cap[6], wc7 = W_cap[7];
    const float bcap = b_cap[0];
    const float wl0 = w_lg[0], wl1 = w_lg[1], wl2 = w_lg[2];

    const int base = b * S_;
    float* out_imp = out + B_ * (S_ - 1);

    // ---- prologue: prime the prefetch pipeline ----
    int t1, r1, t2, r2;
    float qv = 0.f;
    float sv0, sv1, sv2, sv3, tf, af, hf;
    int msk;
    {
        const int t0c = topics[base];
        const int r0c = resps[base];
        t1 = topics[base + 1]; r1 = resps[base + 1];
        t2 = topics[base + 2]; r2 = resps[base + 2];
        if (tid < 32) {
            w_lds[0][tid] = q_matrix[t0c * 32 + tid];
            qv            = q_matrix[t1 * 32 + tid];   // row for step 1
        }
        const float* sp = streams + ((size_t)t0c * 2 + r0c) * 512 + u;
        sv0 = sp[0]; sv1 = sp[128]; sv2 = sp[256]; sv3 = sp[384];
        tf = tf_[base]; af = af_[base]; hf = hf_[base]; msk = masks[base];
    }
    __syncthreads();
    float4 wA = *(const float4*)&w_lds[0][q * 8];
    float4 wB = *(const float4*)&w_lds[0][q * 8 + 4];

    #pragma unroll 1
    for (int s = 0; s < S_; ++s) {
        const int buf = s & 1;

        // ---- issue prefetches for s+1 / s+2 / s+3 (consumed next iter) ----
        const int i1 = base + (s + 1 < S_ ? s + 1 : S_ - 1);
        const int i3 = base + (s + 3 < S_ ? s + 3 : S_ - 1);
        const float* spn = streams + ((size_t)t1 * 2 + r1) * 512 + u;
        const float nsv0 = spn[0], nsv1 = spn[128], nsv2 = spn[256], nsv3 = spn[384];
        const float ntf = tf_[i1], naf = af_[i1], nhf = hf_[i1];
        const int   nmsk = masks[i1];
        const int   t3 = topics[i3], r3 = resps[i3];
        float qv_new = 0.f;
        if (tid < 32) qv_new = q_matrix[t2 * 32 + tid];   // row for step s+2

        // ---- h_tilde: in-thread partial over 8 m's, butterfly over q ----
        float hp = wA.x * H[0] + wA.y * H[1] + wA.z * H[2] + wA.w * H[3]
                 + wB.x * H[4] + wB.y * H[5] + wB.z * H[6] + wB.w * H[7];
        hp += __shfl_xor(hp, 1);
        hp += __shfl_xor(hp, 2);
        if (q == 0) ht_lds[buf][u + ((u >> 5) << 2)] = hp;   // padded slot
        if (tid < 32) w_lds[buf ^ 1][tid] = qv;              // w row for s+1
        __syncthreads();                                     // THE barrier

        // next step's w into regs (written pre-barrier, visible now)
        const float4 wAn = *(const float4*)&w_lds[buf ^ 1][q * 8];
        const float4 wBn = *(const float4*)&w_lds[buf ^ 1][q * 8 + 4];

        // ---- five dot products over this lane's k-slice ----
        float a0 = 0, a1 = 0, a2 = 0, a3 = 0, a4 = 0;
        const float* htb = &ht_lds[buf][q * 36];
        #pragma unroll
        for (int c = 0; c < 8; ++c) {
            const float4 h4 = *(const float4*)(htb + c * 4);
            a0 = fmaf(Wo[c*4+0], h4.x, a0); a0 = fmaf(Wo[c*4+1], h4.y, a0);
            a0 = fmaf(Wo[c*4+2], h4.z, a0); a0 = fmaf(Wo[c*4+3], h4.w, a0);
            a1 = fmaf(Wt[c*4+0], h4.x, a1); a1 = fmaf(Wt[c*4+1], h4.y, a1);
            a1 = fmaf(Wt[c*4+2], h4.z, a1); a1 = fmaf(Wt[c*4+3], h4.w, a1);
            a2 = fmaf(Wa[c*4+0], h4.x, a2); a2 = fmaf(Wa[c*4+1], h4.y, a2);
            a2 = fmaf(Wa[c*4+2], h4.z, a2); a2 = fmaf(Wa[c*4+3], h4.w, a2);
            a3 = fmaf(Wh[c*4+0], h4.x, a3); a3 = fmaf(Wh[c*4+1], h4.y, a3);
            a3 = fmaf(Wh[c*4+2], h4.z, a3); a3 = fmaf(Wh[c*4+3], h4.w, a3);
            a4 = fmaf(Wg[c*4+0], h4.x, a4); a4 = fmaf(Wg[c*4+1], h4.y, a4);
            a4 = fmaf(Wg[c*4+2], h4.z, a4); a4 = fmaf(Wg[c*4+3], h4.w, a4);
        }
        a0 += __shfl_xor(a0, 1); a0 += __shfl_xor(a0, 2);
        a1 += __shfl_xor(a1, 1); a1 += __shfl_xor(a1, 2);
        a2 += __shfl_xor(a2, 1); a2 += __shfl_xor(a2, 2);
        a3 += __shfl_xor(a3, 1); a3 += __shfl_xor(a3, 2);
        a4 += __shfl_xor(a4, 1); a4 += __shfl_xor(a4, 2);

        // ---- epilogue (redundant on all 4 q-lanes of each u) ----
        const float sig = sigmoidf_(a0 + bo);
        const float gt  = tanhf_(a1 + sv0 + tf * wt0 + bt) * tf;
        const float ga  = tanhf_(a2 + sv1 + af * wa0 + ba) * af;
        const float gh  = tanhf_(a3 + sv2 + hf * wh0 + bh) * hf;
        const float capin = wc0*tf + wc1*af + wc2*hf + wc3*(tf*af) + wc4*(tf*hf)
                          + wc5*(af*hf) + wc6*(tf*af*hf) + wc7 + bcap;
        const float cap   = sigmoidf_(capin);
        const float lg    = cap * fmaxf(wl0 * gt + wl1 * ga + wl2 * gh, 0.f);
        const float gamma = sigmoidf_(a4 + sv3 + bg);

        if (msk) {
            H[0] = fmaf(gamma, H[0], wA.x * lg); H[1] = fmaf(gamma, H[1], wA.y * lg);
            H[2] = fmaf(gamma, H[2], wA.z * lg); H[3] = fmaf(gamma, H[3], wA.w * lg);
            H[4] = fmaf(gamma, H[4], wB.x * lg); H[5] = fmaf(gamma, H[5], wB.y * lg);
            H[6] = fmaf(gamma, H[6], wB.z * lg); H[7] = fmaf(gamma, H[7], wB.w * lg);
        }

        // ---- per-wave output partials (each u counted 4x -> *0.25) ----
        float ps = sig, pl = lg;
        #pragma unroll
        for (int o = 32; o > 0; o >>= 1) {
            ps += __shfl_xor(ps, o);
            pl += __shfl_xor(pl, o);
        }
        if ((tid & 63) == 0) {
            red[buf][wv][0] = msk ? ps * 0.25f : 0.f;
            red[buf][wv][1] = msk ? pl * 0.25f : 0.f;
        }
        // deferred write of step s-1's outputs (red[buf^1] visible via barrier)
        if (tid == 0 && s >= 1) {
            float Ps = 0, Is = 0;
            #pragma unroll
            for (int w8 = 0; w8 < 8; ++w8) { Ps += red[buf ^ 1][w8][0]; Is += red[buf ^ 1][w8][1]; }
            out_imp[b * S_ + (s - 1)] = Is * (1.f / 128.f);
            if (s >= 2) out[b * (S_ - 1) + (s - 2)] = Ps * (1.f / 128.f);
        }

        // ---- rotate prefetch pipeline ----
        wA = wAn; wB = wBn;
        sv0 = nsv0; sv1 = nsv1; sv2 = nsv2; sv3 = nsv3;
        tf = ntf; af = naf; hf = nhf; msk = nmsk;
        t1 = t2; r1 = r2; t2 = t3; r2 = r3; qv = qv_new;
    }

    // ---- flush step S_-1 outputs ----
    __syncthreads();
    if (tid == 0) {
        float Ps = 0, Is = 0;
        #pragma unroll
        for (int w8 = 0; w8 < 8; ++w8) { Ps += red[1][w8][0]; Is += red[1][w8][1]; }
        out_imp[b * S_ + (S_ - 1)] = Is * (1.f / 128.f);
        out[b * (S_ - 1) + (S_ - 2)] = Ps * (1.f / 128.f);
    }
}

// ---------------------------------------------------------------------------
extern "C" void kernel_launch(void* const* d_in, const int* in_sizes, int n_in,
                              void* d_out, int out_size, void* d_ws, size_t ws_size,
                              hipStream_t stream)
{
    (void)in_sizes; (void)n_in; (void)out_size; (void)ws_size;

    const int*   topics    = (const int*)  d_in[0];
    const int*   resps     = (const int*)  d_in[1];
    const float* tf        = (const float*)d_in[2];
    const float* af        = (const float*)d_in[3];
    const float* hf        = (const float*)d_in[4];
    const int*   masks     = (const int*)  d_in[5];
    /* d_in[6] = training (ignored) */
    const float* emb_topic = (const float*)d_in[7];
    const float* emb_resps = (const float*)d_in[8];
    const float* q_matrix  = (const float*)d_in[9];
    const float* W_in      = (const float*)d_in[10];
    const float* b_in      = (const float*)d_in[11];
    const float* init_h    = (const float*)d_in[12];
    const float* W_out     = (const float*)d_in[13];
    const float* b_out     = (const float*)d_in[14];
    const float* W_time    = (const float*)d_in[15];
    const float* b_time    = (const float*)d_in[16];
    const float* W_att     = (const float*)d_in[17];
    const float* b_att     = (const float*)d_in[18];
    const float* W_hint    = (const float*)d_in[19];
    const float* b_hint    = (const float*)d_in[20];
    const float* W_cap     = (const float*)d_in[21];
    const float* b_cap     = (const float*)d_in[22];
    const float* w_lg      = (const float*)d_in[23];
    const float* W_gate    = (const float*)d_in[24];
    const float* b_gate    = (const float*)d_in[25];

    float* ws        = (float*)d_ws;
    float* topicAct  = ws;                         // 10000*128
    float* topicGate = topicAct + NT_ * 128;       // 10000*128
    float* respAct   = topicGate + NT_ * 128;      // 256
    float* streams   = respAct + 256;              // 10000*2*512

    prep_topic  <<<NT_ / 8 + 1, 128, 0, stream>>>(emb_topic, emb_resps, W_in, W_gate,
                                                  topicAct, topicGate, respAct);
    prep_streams<<<NT_ / 8,     128, 0, stream>>>(topicAct, topicGate, respAct, b_in,
                                                  W_time, W_att, W_hint, W_gate, streams);
    recurrent   <<<B_, 512, 0, stream>>>(topics, resps, tf, af, hf, masks,
                                         q_matrix, init_h,
                                         W_out, b_out, W_time, b_time,
                                         W_att, b_att, W_hint, b_hint,
                                         W_cap, b_cap, w_lg, W_gate, b_gate,
                                         streams, (float*)d_out);
}

// Round 3
// 948.598 us; speedup vs baseline: 1.1959x; 1.0138x over previous
//
#include <hip/hip_runtime.h>
#include <hip/hip_bf16.h>

#define NT_ 10000
#define B_  128
#define S_  500

// ---------------------------------------------------------------------------
// Kernel A: per-topic precompute
//   topicAct[t][u]  = emb_topic[t] @ W_in[0:128]          (a's topic part)
//   topicGate[t][u] = emb_topic[t] @ W_gate[256:384]      (gamma's e part)
// last block (blk==1250): respAct[r][u] = emb_resps[r] @ W_in[128:256]
// ---------------------------------------------------------------------------
__global__ __launch_bounds__(128) void prep_topic(
    const float* __restrict__ emb_topic,
    const float* __restrict__ emb_resps,
    const float* __restrict__ W_in,
    const float* __restrict__ W_gate,
    float* __restrict__ topicAct,
    float* __restrict__ topicGate,
    float* __restrict__ respAct)
{
    const int u = threadIdx.x;
    __shared__ float e[8][128];
    const int blk = blockIdx.x;

    if (blk == NT_ / 8) {
        e[0][u] = emb_resps[u];
        e[1][u] = emb_resps[128 + u];
        __syncthreads();
        float a0 = 0.f, a1 = 0.f;
        for (int k = 0; k < 128; ++k) {
            float wv = W_in[(128 + k) * 128 + u];
            a0 += e[0][k] * wv;
            a1 += e[1][k] * wv;
        }
        respAct[u]       = a0;
        respAct[128 + u] = a1;
        return;
    }

    const int t0 = blk * 8;
    #pragma unroll
    for (int j = 0; j < 8; ++j) e[j][u] = emb_topic[(t0 + j) * 128 + u];
    __syncthreads();

    float accA[8], accG[8];
    #pragma unroll
    for (int j = 0; j < 8; ++j) { accA[j] = 0.f; accG[j] = 0.f; }

    for (int k = 0; k < 128; ++k) {
        float wa = W_in[k * 128 + u];
        float wg = W_gate[(256 + k) * 128 + u];
        #pragma unroll
        for (int j = 0; j < 8; ++j) {
            accA[j] += e[j][k] * wa;
            accG[j] += e[j][k] * wg;
        }
    }
    #pragma unroll
    for (int j = 0; j < 8; ++j) {
        topicAct [(t0 + j) * 128 + u] = accA[j];
        topicGate[(t0 + j) * 128 + u] = accG[j];
    }
}

// ---------------------------------------------------------------------------
// Kernel B: per-(topic,resp) streams.
//   a = relu(topicAct[t] + respAct[r] + b_in)
//   streams[(t*2+r)*512 + mat*128 + u]:
//     mat0: a @ W_time[1:129]    mat1: a @ W_att[1:129]
//     mat2: a @ W_hint[1:129]    mat3: a @ W_gate[128:256] + topicGate[t]
// ---------------------------------------------------------------------------
__global__ __launch_bounds__(128) void prep_streams(
    const float* __restrict__ topicAct,
    const float* __restrict__ topicGate,
    const float* __restrict__ respAct,
    const float* __restrict__ b_in,
    const float* __restrict__ W_time,
    const float* __restrict__ W_att,
    const float* __restrict__ W_hint,
    const float* __restrict__ W_gate,
    float* __restrict__ streams)
{
    const int u  = threadIdx.x;
    const int t0 = blockIdx.x * 8;
    __shared__ float a_lds[16][128];

    const float bi = b_in[u];
    const float r0 = respAct[u];
    const float r1 = respAct[128 + u];
    #pragma unroll
    for (int j = 0; j < 8; ++j) {
        float ta = topicAct[(t0 + j) * 128 + u];
        a_lds[j * 2 + 0][u] = fmaxf(ta + r0 + bi, 0.f);
        a_lds[j * 2 + 1][u] = fmaxf(ta + r1 + bi, 0.f);
    }
    __syncthreads();

    const float* Wm[4] = { W_time + 128 + u, W_att + 128 + u,
                           W_hint + 128 + u, W_gate + 128 * 128 + u };

    for (int mat = 0; mat < 4; ++mat) {
        const float* Wp = Wm[mat];
        float acc[16];
        #pragma unroll
        for (int r = 0; r < 16; ++r) acc[r] = 0.f;
        for (int k = 0; k < 128; ++k) {
            float wv = Wp[(size_t)k * 128];
            #pragma unroll
            for (int r = 0; r < 16; ++r) acc[r] += a_lds[r][k] * wv;
        }
        #pragma unroll
        for (int r = 0; r < 16; ++r) {
            float v = acc[r];
            int   t = t0 + (r >> 1);
            if (mat == 3) v += topicGate[t * 128 + u];
            streams[((size_t)t * 2 + (r & 1)) * 512 + mat * 128 + u] = v;
        }
    }
}

// ---------------------------------------------------------------------------
// Kernel C: 500-step recurrence. 1 block/batch row, 512 threads.
//   u = tid>>2 (output unit 0..127), q = tid&3 (k-slice of 32).
// Cross-q reductions are shfl_xor(1)/shfl_xor(2); ONE barrier/step.
// Weights truly register-resident (asm keep-alive defeats load-remat).
// In-loop barrier waits lgkmcnt only (global prefetches stay in flight).
// ---------------------------------------------------------------------------
__device__ __forceinline__ float sigmoidf_(float x) {
    return 1.f / (1.f + __expf(-x));
}
__device__ __forceinline__ float tanhf_(float x) {
    float e = __expf(2.f * x);
    return 1.f - 2.f / (e + 1.f);
}

// LDS-only barrier: make our DS writes visible, sync, but do NOT drain vmcnt
// (in-flight global prefetches keep flying across the barrier).
#define LDS_BARRIER()                                         \
    do {                                                      \
        asm volatile("s_waitcnt lgkmcnt(0)" ::: "memory");    \
        __builtin_amdgcn_s_barrier();                         \
        asm volatile("" ::: "memory");                        \
    } while (0)

__global__ __launch_bounds__(512) __attribute__((amdgpu_waves_per_eu(2, 2)))
void recurrent(
    const int*   __restrict__ topics, const int* __restrict__ resps,
    const float* __restrict__ tf_, const float* __restrict__ af_,
    const float* __restrict__ hf_, const int* __restrict__ masks,
    const float* __restrict__ q_matrix, const float* __restrict__ init_h,
    const float* __restrict__ W_out,  const float* __restrict__ b_out,
    const float* __restrict__ W_time, const float* __restrict__ b_time,
    const float* __restrict__ W_att,  const float* __restrict__ b_att,
    const float* __restrict__ W_hint, const float* __restrict__ b_hint,
    const float* __restrict__ W_cap,  const float* __restrict__ b_cap,
    const float* __restrict__ w_lg,
    const float* __restrict__ W_gate, const float* __restrict__ b_gate,
    const float* __restrict__ streams,
    float* __restrict__ out)
{
    const int tid = threadIdx.x;
    const int u   = tid >> 2;     // 0..127
    const int q   = tid & 3;      // 0..3
    const int wv  = tid >> 6;     // wave 0..7
    const int b   = blockIdx.x;

    __shared__ float w_lds[2][32];
    __shared__ __align__(16) float ht_lds[2][144];   // 4 slices of 32, +4 pad each
    __shared__ float red[2][8][2];

    // ---- register-resident weights: k-slice [q*32, q*32+32) ----
    float Wo[32], Wt[32], Wa[32], Wh[32], Wg[32];
    const int kb = q * 32;
    #pragma unroll
    for (int kk = 0; kk < 32; ++kk) {
        Wo[kk] = W_out [(kb + kk) * 128 + u];
        Wt[kk] = W_time[(129 + kb + kk) * 128 + u];
        Wa[kk] = W_att [(129 + kb + kk) * 128 + u];
        Wh[kk] = W_hint[(129 + kb + kk) * 128 + u];
        Wg[kk] = W_gate[(kb + kk) * 128 + u];
    }
    // Defeat load-rematerialization: asm-defined values must stay live in
    // registers; the RA can no longer re-issue the global loads per step.
    #pragma unroll
    for (int kk = 0; kk < 32; ++kk) {
        asm volatile("" : "+v"(Wo[kk]), "+v"(Wt[kk]), "+v"(Wa[kk]),
                          "+v"(Wh[kk]), "+v"(Wg[kk]));
    }

    // H[m][u] for m = q*8 .. q*8+7
    float H[8];
    #pragma unroll
    for (int j = 0; j < 8; ++j) H[j] = init_h[(q * 8 + j) * 128 + u];

    // per-u epilogue constants (all lanes — epilogue is redundant over q)
    const float bo = b_out[u], bt = b_time[u], ba = b_att[u], bh = b_hint[u], bg = b_gate[u];
    const float wt0 = W_time[u], wa0 = W_att[u], wh0 = W_hint[u];
    const float wc0 = W_cap[0], wc1 = W_cap[1], wc2 = W_cap[2], wc3 = W_cap[3];
    const float wc4 = W_cap[4], wc5 = W_cap[5], wc6 = W_cap[6], wc7 = W_cap[7];
    const float bcap = b_cap[0];
    const float wl0 = w_lg[0], wl1 = w_lg[1], wl2 = w_lg[2];

    const int base = b * S_;
    float* out_imp = out + B_ * (S_ - 1);

    // ---- prologue: prime the prefetch pipeline ----
    int t1, r1, t2, r2;
    float qv = 0.f;
    float sv0, sv1, sv2, sv3, tf, af, hf;
    int msk;
    {
        const int t0c = topics[base];
        const int r0c = resps[base];
        t1 = topics[base + 1]; r1 = resps[base + 1];
        t2 = topics[base + 2]; r2 = resps[base + 2];
        if (tid < 32) {
            w_lds[0][tid] = q_matrix[t0c * 32 + tid];
            qv            = q_matrix[t1 * 32 + tid];   // row for step 1
        }
        const float* sp = streams + ((size_t)t0c * 2 + r0c) * 512 + u;
        sv0 = sp[0]; sv1 = sp[128]; sv2 = sp[256]; sv3 = sp[384];
        tf = tf_[base]; af = af_[base]; hf = hf_[base]; msk = masks[base];
    }
    __syncthreads();
    float4 wA = *(const float4*)&w_lds[0][q * 8];
    float4 wB = *(const float4*)&w_lds[0][q * 8 + 4];

    #pragma unroll 1
    for (int s = 0; s < S_; ++s) {
        const int buf = s & 1;

        // ---- issue prefetches for s+1 / s+2 / s+3 (consumed next iter) ----
        const int i1 = base + (s + 1 < S_ ? s + 1 : S_ - 1);
        const int i3 = base + (s + 3 < S_ ? s + 3 : S_ - 1);
        const float* spn = streams + ((size_t)t1 * 2 + r1) * 512 + u;
        const float nsv0 = spn[0], nsv1 = spn[128], nsv2 = spn[256], nsv3 = spn[384];
        const float ntf = tf_[i1], naf = af_[i1], nhf = hf_[i1];
        const int   nmsk = masks[i1];
        const int   t3 = topics[i3], r3 = resps[i3];
        float qv_new = 0.f;
        if (tid < 32) qv_new = q_matrix[t2 * 32 + tid];   // row for step s+2

        // ---- h_tilde: in-thread partial over 8 m's, butterfly over q ----
        float hp = wA.x * H[0] + wA.y * H[1] + wA.z * H[2] + wA.w * H[3]
                 + wB.x * H[4] + wB.y * H[5] + wB.z * H[6] + wB.w * H[7];
        hp += __shfl_xor(hp, 1);
        hp += __shfl_xor(hp, 2);
        if (q == 0) ht_lds[buf][u + ((u >> 5) << 2)] = hp;   // padded slot
        if (tid < 32) w_lds[buf ^ 1][tid] = qv;              // w row for s+1
        LDS_BARRIER();                                       // THE barrier

        // next step's w into regs (written pre-barrier, visible now)
        const float4 wAn = *(const float4*)&w_lds[buf ^ 1][q * 8];
        const float4 wBn = *(const float4*)&w_lds[buf ^ 1][q * 8 + 4];

        // ---- five dot products over this lane's k-slice ----
        float a0 = 0, a1 = 0, a2 = 0, a3 = 0, a4 = 0;
        const float* htb = &ht_lds[buf][q * 36];
        #pragma unroll
        for (int c = 0; c < 8; ++c) {
            const float4 h4 = *(const float4*)(htb + c * 4);
            a0 = fmaf(Wo[c*4+0], h4.x, a0); a0 = fmaf(Wo[c*4+1], h4.y, a0);
            a0 = fmaf(Wo[c*4+2], h4.z, a0); a0 = fmaf(Wo[c*4+3], h4.w, a0);
            a1 = fmaf(Wt[c*4+0], h4.x, a1); a1 = fmaf(Wt[c*4+1], h4.y, a1);
            a1 = fmaf(Wt[c*4+2], h4.z, a1); a1 = fmaf(Wt[c*4+3], h4.w, a1);
            a2 = fmaf(Wa[c*4+0], h4.x, a2); a2 = fmaf(Wa[c*4+1], h4.y, a2);
            a2 = fmaf(Wa[c*4+2], h4.z, a2); a2 = fmaf(Wa[c*4+3], h4.w, a2);
            a3 = fmaf(Wh[c*4+0], h4.x, a3); a3 = fmaf(Wh[c*4+1], h4.y, a3);
            a3 = fmaf(Wh[c*4+2], h4.z, a3); a3 = fmaf(Wh[c*4+3], h4.w, a3);
            a4 = fmaf(Wg[c*4+0], h4.x, a4); a4 = fmaf(Wg[c*4+1], h4.y, a4);
            a4 = fmaf(Wg[c*4+2], h4.z, a4); a4 = fmaf(Wg[c*4+3], h4.w, a4);
        }
        a0 += __shfl_xor(a0, 1); a0 += __shfl_xor(a0, 2);
        a1 += __shfl_xor(a1, 1); a1 += __shfl_xor(a1, 2);
        a2 += __shfl_xor(a2, 1); a2 += __shfl_xor(a2, 2);
        a3 += __shfl_xor(a3, 1); a3 += __shfl_xor(a3, 2);
        a4 += __shfl_xor(a4, 1); a4 += __shfl_xor(a4, 2);

        // ---- epilogue (redundant on all 4 q-lanes of each u) ----
        const float sig = sigmoidf_(a0 + bo);
        const float gt  = tanhf_(a1 + sv0 + tf * wt0 + bt) * tf;
        const float ga  = tanhf_(a2 + sv1 + af * wa0 + ba) * af;
        const float gh  = tanhf_(a3 + sv2 + hf * wh0 + bh) * hf;
        const float capin = wc0*tf + wc1*af + wc2*hf + wc3*(tf*af) + wc4*(tf*hf)
                          + wc5*(af*hf) + wc6*(tf*af*hf) + wc7 + bcap;
        const float cap   = sigmoidf_(capin);
        const float lg    = cap * fmaxf(wl0 * gt + wl1 * ga + wl2 * gh, 0.f);
        const float gamma = sigmoidf_(a4 + sv3 + bg);

        if (msk) {
            H[0] = fmaf(gamma, H[0], wA.x * lg); H[1] = fmaf(gamma, H[1], wA.y * lg);
            H[2] = fmaf(gamma, H[2], wA.z * lg); H[3] = fmaf(gamma, H[3], wA.w * lg);
            H[4] = fmaf(gamma, H[4], wB.x * lg); H[5] = fmaf(gamma, H[5], wB.y * lg);
            H[6] = fmaf(gamma, H[6], wB.z * lg); H[7] = fmaf(gamma, H[7], wB.w * lg);
        }

        // ---- per-wave output partials (each u counted 4x -> *0.25) ----
        float ps = sig, pl = lg;
        #pragma unroll
        for (int o = 32; o > 0; o >>= 1) {
            ps += __shfl_xor(ps, o);
            pl += __shfl_xor(pl, o);
        }
        if ((tid & 63) == 0) {
            red[buf][wv][0] = msk ? ps * 0.25f : 0.f;
            red[buf][wv][1] = msk ? pl * 0.25f : 0.f;
        }
        // deferred write of step s-1's outputs (red[buf^1] visible via barrier)
        if (tid == 0 && s >= 1) {
            float Ps = 0, Is = 0;
            #pragma unroll
            for (int w8 = 0; w8 < 8; ++w8) { Ps += red[buf ^ 1][w8][0]; Is += red[buf ^ 1][w8][1]; }
            out_imp[b * S_ + (s - 1)] = Is * (1.f / 128.f);
            if (s >= 2) out[b * (S_ - 1) + (s - 2)] = Ps * (1.f / 128.f);
        }

        // ---- rotate prefetch pipeline ----
        wA = wAn; wB = wBn;
        sv0 = nsv0; sv1 = nsv1; sv2 = nsv2; sv3 = nsv3;
        tf = ntf; af = naf; hf = nhf; msk = nmsk;
        t1 = t2; r1 = r2; t2 = t3; r2 = r3; qv = qv_new;
    }

    // ---- flush step S_-1 outputs ----
    __syncthreads();
    if (tid == 0) {
        float Ps = 0, Is = 0;
        #pragma unroll
        for (int w8 = 0; w8 < 8; ++w8) { Ps += red[1][w8][0]; Is += red[1][w8][1]; }
        out_imp[b * S_ + (S_ - 1)] = Is * (1.f / 128.f);
        out[b * (S_ - 1) + (S_ - 2)] = Ps * (1.f / 128.f);
    }
}

// ---------------------------------------------------------------------------
extern "C" void kernel_launch(void* const* d_in, const int* in_sizes, int n_in,
                              void* d_out, int out_size, void* d_ws, size_t ws_size,
                              hipStream_t stream)
{
    (void)in_sizes; (void)n_in; (void)out_size; (void)ws_size;

    const int*   topics    = (const int*)  d_in[0];
    const int*   resps     = (const int*)  d_in[1];
    const float* tf        = (const float*)d_in[2];
    const float* af        = (const float*)d_in[3];
    const float* hf        = (const float*)d_in[4];
    const int*   masks     = (const int*)  d_in[5];
    /* d_in[6] = training (ignored) */
    const float* emb_topic = (const float*)d_in[7];
    const float* emb_resps = (const float*)d_in[8];
    const float* q_matrix  = (const float*)d_in[9];
    const float* W_in      = (const float*)d_in[10];
    const float* b_in      = (const float*)d_in[11];
    const float* init_h    = (const float*)d_in[12];
    const float* W_out     = (const float*)d_in[13];
    const float* b_out     = (const float*)d_in[14];
    const float* W_time    = (const float*)d_in[15];
    const float* b_time    = (const float*)d_in[16];
    const float* W_att     = (const float*)d_in[17];
    const float* b_att     = (const float*)d_in[18];
    const float* W_hint    = (const float*)d_in[19];
    const float* b_hint    = (const float*)d_in[20];
    const float* W_cap     = (const float*)d_in[21];
    const float* b_cap     = (const float*)d_in[22];
    const float* w_lg      = (const float*)d_in[23];
    const float* W_gate    = (const float*)d_in[24];
    const float* b_gate    = (const float*)d_in[25];

    float* ws        = (float*)d_ws;
    float* topicAct  = ws;                         // 10000*128
    float* topicGate = topicAct + NT_ * 128;       // 10000*128
    float* respAct   = topicGate + NT_ * 128;      // 256
    float* streams   = respAct + 256;              // 10000*2*512

    prep_topic  <<<NT_ / 8 + 1, 128, 0, stream>>>(emb_topic, emb_resps, W_in, W_gate,
                                                  topicAct, topicGate, respAct);
    prep_streams<<<NT_ / 8,     128, 0, stream>>>(topicAct, topicGate, respAct, b_in,
                                                  W_time, W_att, W_hint, W_gate, streams);
    recurrent   <<<B_, 512, 0, stream>>>(topics, resps, tf, af, hf, masks,
                                         q_matrix, init_h,
                                         W_out, b_out, W_time, b_time,
                                         W_att, b_att, W_hint, b_hint,
                                         W_cap, b_cap, w_lg, W_gate, b_gate,
                                         streams, (float*)d_out);
}

// Round 4
// 878.570 us; speedup vs baseline: 1.2912x; 1.0797x over previous
//
#include <hip/hip_runtime.h>
#include <hip/hip_bf16.h>

#define NT_ 10000
#define B_  128
#define S_  500

typedef _Float16 h2_t __attribute__((ext_vector_type(2)));
typedef unsigned int uint32;

__device__ __forceinline__ uint32 pack2(float a, float b) {
    return __builtin_bit_cast(uint32, __builtin_amdgcn_cvt_pkrtz(a, b));
}
__device__ __forceinline__ float dot2(uint32 w, uint32 h, float acc) {
#if __has_builtin(__builtin_amdgcn_fdot2)
    return __builtin_amdgcn_fdot2(__builtin_bit_cast(h2_t, w),
                                  __builtin_bit_cast(h2_t, h), acc, false);
#else
    h2_t wv = __builtin_bit_cast(h2_t, w), hv = __builtin_bit_cast(h2_t, h);
    acc = fmaf((float)wv[0], (float)hv[0], acc);
    return fmaf((float)wv[1], (float)hv[1], acc);
#endif
}

// ---------------------------------------------------------------------------
// Kernel A: per-topic precompute. blockIdx.y = mode (0: topicAct, 1: topicGate)
//   topicAct[t][u]  = emb_topic[t] @ W_in[0:128]
//   topicGate[t][u] = emb_topic[t] @ W_gate[256:384]
// mode 0, blk==NT_/8: respAct[r][u] = emb_resps[r] @ W_in[128:256]
// ---------------------------------------------------------------------------
__global__ __launch_bounds__(128) void prep_topic(
    const float* __restrict__ emb_topic,
    const float* __restrict__ emb_resps,
    const float* __restrict__ W_in,
    const float* __restrict__ W_gate,
    float* __restrict__ topicAct,
    float* __restrict__ topicGate,
    float* __restrict__ respAct)
{
    const int u    = threadIdx.x;
    const int blk  = blockIdx.x;
    const int mode = blockIdx.y;
    __shared__ float e[8][128];

    if (blk == NT_ / 8) {
        if (mode) return;
        e[0][u] = emb_resps[u];
        e[1][u] = emb_resps[128 + u];
        __syncthreads();
        float a0 = 0.f, a1 = 0.f;
        for (int k = 0; k < 128; ++k) {
            float wv = W_in[(128 + k) * 128 + u];
            a0 += e[0][k] * wv;
            a1 += e[1][k] * wv;
        }
        respAct[u]       = a0;
        respAct[128 + u] = a1;
        return;
    }

    const int t0 = blk * 8;
    #pragma unroll
    for (int j = 0; j < 8; ++j) e[j][u] = emb_topic[(t0 + j) * 128 + u];
    __syncthreads();

    const float* __restrict__ W = mode ? (W_gate + 256 * 128) : W_in;
    float acc[8];
    #pragma unroll
    for (int j = 0; j < 8; ++j) acc[j] = 0.f;
    for (int k = 0; k < 128; ++k) {
        float wv = W[k * 128 + u];
        #pragma unroll
        for (int j = 0; j < 8; ++j) acc[j] += e[j][k] * wv;
    }
    float* __restrict__ dst = mode ? topicGate : topicAct;
    #pragma unroll
    for (int j = 0; j < 8; ++j) dst[(t0 + j) * 128 + u] = acc[j];
}

// ---------------------------------------------------------------------------
// Kernel B: per-(topic,resp) streams. blockIdx.y = mat (0..3).
//   a = relu(topicAct[t] + respAct[r] + b_in)
//   streams[(t*2+r)*512 + mat*128 + u]:
//     mat0: a@W_time[1:129]  mat1: a@W_att[1:129]
//     mat2: a@W_hint[1:129]  mat3: a@W_gate[128:256] + topicGate[t]
// ---------------------------------------------------------------------------
__global__ __launch_bounds__(128) void prep_streams(
    const float* __restrict__ topicAct,
    const float* __restrict__ topicGate,
    const float* __restrict__ respAct,
    const float* __restrict__ b_in,
    const float* __restrict__ W_time,
    const float* __restrict__ W_att,
    const float* __restrict__ W_hint,
    const float* __restrict__ W_gate,
    float* __restrict__ streams)
{
    const int u   = threadIdx.x;
    const int t0  = blockIdx.x * 8;
    const int mat = blockIdx.y;
    __shared__ float a_lds[16][128];

    const float bi = b_in[u];
    const float r0 = respAct[u];
    const float r1 = respAct[128 + u];
    #pragma unroll
    for (int j = 0; j < 8; ++j) {
        float ta = topicAct[(t0 + j) * 128 + u];
        a_lds[j * 2 + 0][u] = fmaxf(ta + r0 + bi, 0.f);
        a_lds[j * 2 + 1][u] = fmaxf(ta + r1 + bi, 0.f);
    }
    __syncthreads();

    const float* __restrict__ Wp =
        (mat == 0 ? W_time + 128 : mat == 1 ? W_att + 128 :
         mat == 2 ? W_hint + 128 : W_gate + 128 * 128) + u;

    float acc[16];
    #pragma unroll
    for (int r = 0; r < 16; ++r) acc[r] = 0.f;
    for (int k = 0; k < 128; ++k) {
        float wv = Wp[(size_t)k * 128];
        #pragma unroll
        for (int r = 0; r < 16; ++r) acc[r] += a_lds[r][k] * wv;
    }
    #pragma unroll
    for (int r = 0; r < 16; ++r) {
        float v = acc[r];
        int   t = t0 + (r >> 1);
        if (mat == 3) v += topicGate[t * 128 + u];
        streams[((size_t)t * 2 + (r & 1)) * 512 + mat * 128 + u] = v;
    }
}

// ---------------------------------------------------------------------------
// Kernel C: 500-step recurrence. 1 block/batch row, 512 threads.
//   u = tid>>2 (output unit 0..127), q = tid&3 (k-slice of 32).
// Weights f16-PACKED register-resident: 5 x 16 u32 = 80 VGPR/thread
// (the r2/r3 lesson: 160 f32 live values forced scratch spills reloaded
// from L2 every step; 80 fits the 256-VGPR budget of 2 waves/SIMD).
// Inner loop: 80 x v_dot2_f32_f16. One LDS-only barrier/step (no vmcnt
// drain - global prefetches fly across it).
// ---------------------------------------------------------------------------
__device__ __forceinline__ float sigmoidf_(float x) {
    return 1.f / (1.f + __expf(-x));
}
__device__ __forceinline__ float tanhf_(float x) {
    float e = __expf(2.f * x);
    return 1.f - 2.f / (e + 1.f);
}

#define LDS_BARRIER()                                         \
    do {                                                      \
        asm volatile("s_waitcnt lgkmcnt(0)" ::: "memory");    \
        __builtin_amdgcn_s_barrier();                         \
        asm volatile("" ::: "memory");                        \
    } while (0)

__global__ __launch_bounds__(512, 2)
void recurrent(
    const int*   __restrict__ topics, const int* __restrict__ resps,
    const float* __restrict__ tf_, const float* __restrict__ af_,
    const float* __restrict__ hf_, const int* __restrict__ masks,
    const float* __restrict__ q_matrix, const float* __restrict__ init_h,
    const float* __restrict__ W_out,  const float* __restrict__ b_out,
    const float* __restrict__ W_time, const float* __restrict__ b_time,
    const float* __restrict__ W_att,  const float* __restrict__ b_att,
    const float* __restrict__ W_hint, const float* __restrict__ b_hint,
    const float* __restrict__ W_cap,  const float* __restrict__ b_cap,
    const float* __restrict__ w_lg,
    const float* __restrict__ W_gate, const float* __restrict__ b_gate,
    const float* __restrict__ streams,
    float* __restrict__ out)
{
    const int tid = threadIdx.x;
    const int u   = tid >> 2;     // 0..127
    const int q   = tid & 3;      // 0..3
    const int wv  = tid >> 6;     // wave 0..7
    const int b   = blockIdx.x;

    __shared__ float w_lds[2][32];
    __shared__ __align__(16) uint32 ht_pk[2][64];   // f16-pair-packed h_tilde
    __shared__ float red[2][8][2];

    // ---- f16-packed register-resident weights: k-slice [q*32, q*32+32) ----
    uint32 Wo[16], Wt[16], Wa[16], Wh[16], Wg[16];
    const int kb = q * 32;
    #pragma unroll
    for (int i = 0; i < 16; ++i) {
        const int k0 = kb + 2 * i, k1 = k0 + 1;
        Wo[i] = pack2(W_out [k0 * 128 + u],         W_out [k1 * 128 + u]);
        Wt[i] = pack2(W_time[(129 + k0) * 128 + u], W_time[(129 + k1) * 128 + u]);
        Wa[i] = pack2(W_att [(129 + k0) * 128 + u], W_att [(129 + k1) * 128 + u]);
        Wh[i] = pack2(W_hint[(129 + k0) * 128 + u], W_hint[(129 + k1) * 128 + u]);
        Wg[i] = pack2(W_gate[k0 * 128 + u],         W_gate[k1 * 128 + u]);
    }
    // keep-alive: asm-defined values cannot be rematerialized from loads
    #pragma unroll
    for (int i = 0; i < 16; ++i) {
        asm volatile("" : "+v"(Wo[i]), "+v"(Wt[i]), "+v"(Wa[i]),
                          "+v"(Wh[i]), "+v"(Wg[i]));
    }

    // H[m][u] for m = q*8 .. q*8+7
    float H[8];
    #pragma unroll
    for (int j = 0; j < 8; ++j) H[j] = init_h[(q * 8 + j) * 128 + u];

    // per-u epilogue constants (epilogue redundant over the 4 q-lanes)
    const float bo = b_out[u], bt = b_time[u], ba = b_att[u], bh = b_hint[u], bg = b_gate[u];
    const float wt0 = W_time[u], wa0 = W_att[u], wh0 = W_hint[u];
    const float wc0 = W_cap[0], wc1 = W_cap[1], wc2 = W_cap[2], wc3 = W_cap[3];
    const float wc4 = W_cap[4], wc5 = W_cap[5], wc6 = W_cap[6], wc7 = W_cap[7];
    const float bcap = b_cap[0];
    const float wl0 = w_lg[0], wl1 = w_lg[1], wl2 = w_lg[2];

    const int base = b * S_;
    float* out_imp = out + B_ * (S_ - 1);

    // ---- prologue: prime the prefetch pipeline ----
    int t1, r1, t2, r2;
    float qv = 0.f;
    float sv0, sv1, sv2, sv3, tf, af, hf;
    int msk;
    {
        const int t0c = topics[base];
        const int r0c = resps[base];
        t1 = topics[base + 1]; r1 = resps[base + 1];
        t2 = topics[base + 2]; r2 = resps[base + 2];
        if (tid < 32) {
            w_lds[0][tid] = q_matrix[t0c * 32 + tid];
            qv            = q_matrix[t1 * 32 + tid];
        }
        const float* sp = streams + ((size_t)t0c * 2 + r0c) * 512 + u;
        sv0 = sp[0]; sv1 = sp[128]; sv2 = sp[256]; sv3 = sp[384];
        tf = tf_[base]; af = af_[base]; hf = hf_[base]; msk = masks[base];
    }
    __syncthreads();
    float4 wA = *(const float4*)&w_lds[0][q * 8];
    float4 wB = *(const float4*)&w_lds[0][q * 8 + 4];

    #pragma unroll 1
    for (int s = 0; s < S_; ++s) {
        const int buf = s & 1;

        // ---- issue prefetches for s+1 / s+2 / s+3 ----
        const int i1 = base + (s + 1 < S_ ? s + 1 : S_ - 1);
        const int i3 = base + (s + 3 < S_ ? s + 3 : S_ - 1);
        const float* spn = streams + ((size_t)t1 * 2 + r1) * 512 + u;
        const float nsv0 = spn[0], nsv1 = spn[128], nsv2 = spn[256], nsv3 = spn[384];
        const float ntf = tf_[i1], naf = af_[i1], nhf = hf_[i1];
        const int   nmsk = masks[i1];
        const int   t3 = topics[i3], r3 = resps[i3];
        float qv_new = 0.f;
        if (tid < 32) qv_new = q_matrix[t2 * 32 + tid];

        // ---- h_tilde: partial over 8 m's, butterfly over q, f16-pack ----
        float hp = wA.x * H[0] + wA.y * H[1] + wA.z * H[2] + wA.w * H[3]
                 + wB.x * H[4] + wB.y * H[5] + wB.z * H[6] + wB.w * H[7];
        hp += __shfl_xor(hp, 1);
        hp += __shfl_xor(hp, 2);
        const float hp2 = __shfl_down(hp, 4);         // ht of unit u+1
        if (q == 0 && (u & 1) == 0)
            ht_pk[buf][u >> 1] = pack2(hp, hp2);
        if (tid < 32) w_lds[buf ^ 1][tid] = qv;
        LDS_BARRIER();                                // THE barrier

        const float4 wAn = *(const float4*)&w_lds[buf ^ 1][q * 8];
        const float4 wBn = *(const float4*)&w_lds[buf ^ 1][q * 8 + 4];

        // ---- five dot products: 80 x v_dot2_f32_f16 over packed pairs ----
        float a0 = 0, a1 = 0, a2 = 0, a3 = 0, a4 = 0;
        const uint32* htb = &ht_pk[buf][q * 16];
        #pragma unroll
        for (int c = 0; c < 4; ++c) {
            const uint4 h4 = *(const uint4*)(htb + c * 4);
            a0 = dot2(Wo[c*4+0], h4.x, a0); a0 = dot2(Wo[c*4+1], h4.y, a0);
            a0 = dot2(Wo[c*4+2], h4.z, a0); a0 = dot2(Wo[c*4+3], h4.w, a0);
            a1 = dot2(Wt[c*4+0], h4.x, a1); a1 = dot2(Wt[c*4+1], h4.y, a1);
            a1 = dot2(Wt[c*4+2], h4.z, a1); a1 = dot2(Wt[c*4+3], h4.w, a1);
            a2 = dot2(Wa[c*4+0], h4.x, a2); a2 = dot2(Wa[c*4+1], h4.y, a2);
            a2 = dot2(Wa[c*4+2], h4.z, a2); a2 = dot2(Wa[c*4+3], h4.w, a2);
            a3 = dot2(Wh[c*4+0], h4.x, a3); a3 = dot2(Wh[c*4+1], h4.y, a3);
            a3 = dot2(Wh[c*4+2], h4.z, a3); a3 = dot2(Wh[c*4+3], h4.w, a3);
            a4 = dot2(Wg[c*4+0], h4.x, a4); a4 = dot2(Wg[c*4+1], h4.y, a4);
            a4 = dot2(Wg[c*4+2], h4.z, a4); a4 = dot2(Wg[c*4+3], h4.w, a4);
        }
        a0 += __shfl_xor(a0, 1); a0 += __shfl_xor(a0, 2);
        a1 += __shfl_xor(a1, 1); a1 += __shfl_xor(a1, 2);
        a2 += __shfl_xor(a2, 1); a2 += __shfl_xor(a2, 2);
        a3 += __shfl_xor(a3, 1); a3 += __shfl_xor(a3, 2);
        a4 += __shfl_xor(a4, 1); a4 += __shfl_xor(a4, 2);

        // ---- epilogue (redundant on all 4 q-lanes of each u) ----
        const float sig = sigmoidf_(a0 + bo);
        const float gt  = tanhf_(a1 + sv0 + tf * wt0 + bt) * tf;
        const float ga  = tanhf_(a2 + sv1 + af * wa0 + ba) * af;
        const float gh  = tanhf_(a3 + sv2 + hf * wh0 + bh) * hf;
        const float capin = wc0*tf + wc1*af + wc2*hf + wc3*(tf*af) + wc4*(tf*hf)
                          + wc5*(af*hf) + wc6*(tf*af*hf) + wc7 + bcap;
        const float cap   = sigmoidf_(capin);
        const float lg    = cap * fmaxf(wl0 * gt + wl1 * ga + wl2 * gh, 0.f);
        const float gamma = sigmoidf_(a4 + sv3 + bg);

        if (msk) {
            H[0] = fmaf(gamma, H[0], wA.x * lg); H[1] = fmaf(gamma, H[1], wA.y * lg);
            H[2] = fmaf(gamma, H[2], wA.z * lg); H[3] = fmaf(gamma, H[3], wA.w * lg);
            H[4] = fmaf(gamma, H[4], wB.x * lg); H[5] = fmaf(gamma, H[5], wB.y * lg);
            H[6] = fmaf(gamma, H[6], wB.z * lg); H[7] = fmaf(gamma, H[7], wB.w * lg);
        }

        // ---- per-wave output partials (each u counted 4x -> *0.25) ----
        float ps = sig, pl = lg;
        #pragma unroll
        for (int o = 32; o > 0; o >>= 1) {
            ps += __shfl_xor(ps, o);
            pl += __shfl_xor(pl, o);
        }
        if ((tid & 63) == 0) {
            red[buf][wv][0] = msk ? ps * 0.25f : 0.f;
            red[buf][wv][1] = msk ? pl * 0.25f : 0.f;
        }
        // deferred write of step s-1's outputs
        if (tid == 0 && s >= 1) {
            float Ps = 0, Is = 0;
            #pragma unroll
            for (int w8 = 0; w8 < 8; ++w8) { Ps += red[buf ^ 1][w8][0]; Is += red[buf ^ 1][w8][1]; }
            out_imp[b * S_ + (s - 1)] = Is * (1.f / 128.f);
            if (s >= 2) out[b * (S_ - 1) + (s - 2)] = Ps * (1.f / 128.f);
        }

        // ---- rotate prefetch pipeline ----
        wA = wAn; wB = wBn;
        sv0 = nsv0; sv1 = nsv1; sv2 = nsv2; sv3 = nsv3;
        tf = ntf; af = naf; hf = nhf; msk = nmsk;
        t1 = t2; r1 = r2; t2 = t3; r2 = r3; qv = qv_new;
    }

    // ---- flush step S_-1 outputs ----
    __syncthreads();
    if (tid == 0) {
        float Ps = 0, Is = 0;
        #pragma unroll
        for (int w8 = 0; w8 < 8; ++w8) { Ps += red[1][w8][0]; Is += red[1][w8][1]; }
        out_imp[b * S_ + (S_ - 1)] = Is * (1.f / 128.f);
        out[b * (S_ - 1) + (S_ - 2)] = Ps * (1.f / 128.f);
    }
}

// ---------------------------------------------------------------------------
extern "C" void kernel_launch(void* const* d_in, const int* in_sizes, int n_in,
                              void* d_out, int out_size, void* d_ws, size_t ws_size,
                              hipStream_t stream)
{
    (void)in_sizes; (void)n_in; (void)out_size; (void)ws_size;

    const int*   topics    = (const int*)  d_in[0];
    const int*   resps     = (const int*)  d_in[1];
    const float* tf        = (const float*)d_in[2];
    const float* af        = (const float*)d_in[3];
    const float* hf        = (const float*)d_in[4];
    const int*   masks     = (const int*)  d_in[5];
    /* d_in[6] = training (ignored) */
    const float* emb_topic = (const float*)d_in[7];
    const float* emb_resps = (const float*)d_in[8];
    const float* q_matrix  = (const float*)d_in[9];
    const float* W_in      = (const float*)d_in[10];
    const float* b_in      = (const float*)d_in[11];
    const float* init_h    = (const float*)d_in[12];
    const float* W_out     = (const float*)d_in[13];
    const float* b_out     = (const float*)d_in[14];
    const float* W_time    = (const float*)d_in[15];
    const float* b_time    = (const float*)d_in[16];
    const float* W_att     = (const float*)d_in[17];
    const float* b_att     = (const float*)d_in[18];
    const float* W_hint    = (const float*)d_in[19];
    const float* b_hint    = (const float*)d_in[20];
    const float* W_cap     = (const float*)d_in[21];
    const float* b_cap     = (const float*)d_in[22];
    const float* w_lg      = (const float*)d_in[23];
    const float* W_gate    = (const float*)d_in[24];
    const float* b_gate    = (const float*)d_in[25];

    float* ws        = (float*)d_ws;
    float* topicAct  = ws;                         // 10000*128
    float* topicGate = topicAct + NT_ * 128;       // 10000*128
    float* respAct   = topicGate + NT_ * 128;      // 256
    float* streams   = respAct + 256;              // 10000*2*512

    prep_topic  <<<dim3(NT_ / 8 + 1, 2), 128, 0, stream>>>(
        emb_topic, emb_resps, W_in, W_gate, topicAct, topicGate, respAct);
    prep_streams<<<dim3(NT_ / 8, 4),     128, 0, stream>>>(
        topicAct, topicGate, respAct, b_in,
        W_time, W_att, W_hint, W_gate, streams);
    recurrent   <<<B_, 512, 0, stream>>>(topics, resps, tf, af, hf, masks,
                                         q_matrix, init_h,
                                         W_out, b_out, W_time, b_time,
                                         W_att, b_att, W_hint, b_hint,
                                         W_cap, b_cap, w_lg, W_gate, b_gate,
                                         streams, (float*)d_out);
}

// Round 5
// 736.475 us; speedup vs baseline: 1.5403x; 1.1929x over previous
//
#include <hip/hip_runtime.h>
#include <hip/hip_bf16.h>

#define NT_ 10000
#define B_  128
#define S_  500

typedef _Float16 h2_t __attribute__((ext_vector_type(2)));
typedef unsigned int uint32;

__device__ __forceinline__ uint32 pack2(float a, float b) {
    return __builtin_bit_cast(uint32, __builtin_amdgcn_cvt_pkrtz(a, b));
}
__device__ __forceinline__ float dot2(uint32 w, uint32 h, float acc) {
#if __has_builtin(__builtin_amdgcn_fdot2)
    return __builtin_amdgcn_fdot2(__builtin_bit_cast(h2_t, w),
                                  __builtin_bit_cast(h2_t, h), acc, false);
#else
    h2_t wv = __builtin_bit_cast(h2_t, w), hv = __builtin_bit_cast(h2_t, h);
    acc = fmaf((float)wv[0], (float)hv[0], acc);
    return fmaf((float)wv[1], (float)hv[1], acc);
#endif
}

// ---------------------------------------------------------------------------
// Kernel A: per-topic precompute (blockIdx.y = 0: topicAct, 1: topicGate)
// ---------------------------------------------------------------------------
__global__ __launch_bounds__(128) void prep_topic(
    const float* __restrict__ emb_topic,
    const float* __restrict__ emb_resps,
    const float* __restrict__ W_in,
    const float* __restrict__ W_gate,
    float* __restrict__ topicAct,
    float* __restrict__ topicGate,
    float* __restrict__ respAct)
{
    const int u    = threadIdx.x;
    const int blk  = blockIdx.x;
    const int mode = blockIdx.y;
    __shared__ float e[8][128];

    if (blk == NT_ / 8) {
        if (mode) return;
        e[0][u] = emb_resps[u];
        e[1][u] = emb_resps[128 + u];
        __syncthreads();
        float a0 = 0.f, a1 = 0.f;
        for (int k = 0; k < 128; ++k) {
            float wv = W_in[(128 + k) * 128 + u];
            a0 += e[0][k] * wv;
            a1 += e[1][k] * wv;
        }
        respAct[u]       = a0;
        respAct[128 + u] = a1;
        return;
    }

    const int t0 = blk * 8;
    #pragma unroll
    for (int j = 0; j < 8; ++j) e[j][u] = emb_topic[(t0 + j) * 128 + u];
    __syncthreads();

    const float* __restrict__ W = mode ? (W_gate + 256 * 128) : W_in;
    float acc[8];
    #pragma unroll
    for (int j = 0; j < 8; ++j) acc[j] = 0.f;
    for (int k = 0; k < 128; ++k) {
        float wv = W[k * 128 + u];
        #pragma unroll
        for (int j = 0; j < 8; ++j) acc[j] += e[j][k] * wv;
    }
    float* __restrict__ dst = mode ? topicGate : topicAct;
    #pragma unroll
    for (int j = 0; j < 8; ++j) dst[(t0 + j) * 128 + u] = acc[j];
}

// ---------------------------------------------------------------------------
// Kernel B: per-(topic,resp) streams (blockIdx.y = mat 0..3)
//   streams[(t*2+r)*512 + m*128 + u]: m0: a@W_time[1:129]  m1: a@W_att[1:129]
//                                     m2: a@W_hint[1:129]  m3: a@W_gate[128:256]+topicGate
// ---------------------------------------------------------------------------
__global__ __launch_bounds__(128) void prep_streams(
    const float* __restrict__ topicAct,
    const float* __restrict__ topicGate,
    const float* __restrict__ respAct,
    const float* __restrict__ b_in,
    const float* __restrict__ W_time,
    const float* __restrict__ W_att,
    const float* __restrict__ W_hint,
    const float* __restrict__ W_gate,
    float* __restrict__ streams)
{
    const int u   = threadIdx.x;
    const int t0  = blockIdx.x * 8;
    const int mat = blockIdx.y;
    __shared__ float a_lds[16][128];

    const float bi = b_in[u];
    const float r0 = respAct[u];
    const float r1 = respAct[128 + u];
    #pragma unroll
    for (int j = 0; j < 8; ++j) {
        float ta = topicAct[(t0 + j) * 128 + u];
        a_lds[j * 2 + 0][u] = fmaxf(ta + r0 + bi, 0.f);
        a_lds[j * 2 + 1][u] = fmaxf(ta + r1 + bi, 0.f);
    }
    __syncthreads();

    const float* __restrict__ Wp =
        (mat == 0 ? W_time + 128 : mat == 1 ? W_att + 128 :
         mat == 2 ? W_hint + 128 : W_gate + 128 * 128) + u;

    float acc[16];
    #pragma unroll
    for (int r = 0; r < 16; ++r) acc[r] = 0.f;
    for (int k = 0; k < 128; ++k) {
        float wv = Wp[(size_t)k * 128];
        #pragma unroll
        for (int r = 0; r < 16; ++r) acc[r] += a_lds[r][k] * wv;
    }
    #pragma unroll
    for (int r = 0; r < 16; ++r) {
        float v = acc[r];
        int   t = t0 + (r >> 1);
        if (mat == 3) v += topicGate[t * 128 + u];
        streams[((size_t)t * 2 + (r & 1)) * 512 + mat * 128 + u] = v;
    }
}

// ---------------------------------------------------------------------------
// Kernel C: 500-step recurrence. 1 block/row, 512 threads = 128 u x 4 roles.
//   mat0 -> W_out/sig (+gate k 0:32)    mat1 -> W_time/gt (+gate k 32:64)
//   mat2 -> W_att/ga  (+gate k 64:96)   mat3 -> W_hint/gh (+gate k 96:128)
// Full k=128 dot in-lane (no reduce for a0-a3); gate 4-way split (2 shfl).
// Three tanh's run in PARALLEL lanes. Per-row scalars/indices LDS-preloaded;
// stream/q_matrix gathers 2-step-deep register pipeline. Outputs via 8-slot
// LDS ring, reduced every 4 steps by the 8 waves (no per-step butterfly).
// ---------------------------------------------------------------------------
__device__ __forceinline__ float sigmoidf_(float x) {
    return 1.f / (1.f + __expf(-x));
}
__device__ __forceinline__ float tanhf_(float x) {
    float e = __expf(2.f * x);
    return 1.f - 2.f / (e + 1.f);
}

#define LDS_BARRIER()                                         \
    do {                                                      \
        asm volatile("s_waitcnt lgkmcnt(0)" ::: "memory");    \
        __builtin_amdgcn_s_barrier();                         \
        asm volatile("" ::: "memory");                        \
    } while (0)

__global__ __launch_bounds__(512) __attribute__((amdgpu_waves_per_eu(2, 2)))
void recurrent(
    const int*   __restrict__ topics, const int* __restrict__ resps,
    const float* __restrict__ tf_, const float* __restrict__ af_,
    const float* __restrict__ hf_, const int* __restrict__ masks,
    const float* __restrict__ q_matrix, const float* __restrict__ init_h,
    const float* __restrict__ W_out,  const float* __restrict__ b_out,
    const float* __restrict__ W_time, const float* __restrict__ b_time,
    const float* __restrict__ W_att,  const float* __restrict__ b_att,
    const float* __restrict__ W_hint, const float* __restrict__ b_hint,
    const float* __restrict__ W_cap,  const float* __restrict__ b_cap,
    const float* __restrict__ w_lg,
    const float* __restrict__ W_gate, const float* __restrict__ b_gate,
    const float* __restrict__ streams,
    float* __restrict__ out)
{
    const int tid  = threadIdx.x;
    const int u    = tid >> 2;      // 0..127
    const int mat  = tid & 3;       // role
    const int lane = tid & 63;
    const int wv   = tid >> 6;      // wave 0..7
    const int b    = blockIdx.x;

    __shared__ int    sb_lds[S_];            // (topic*2+resp)*512
    __shared__ int    qb_lds[S_];            // topic*32
    __shared__ float4 sc_lds[S_];            // {tf, af, hf, mask}
    __shared__ float  w_lds[2][32];
    __shared__ __align__(16) uint32 ht_pk[2][64];
    __shared__ float  outbuf[8][128][2];     // 8-slot ring: no read/write overlap

    const int base = b * S_;

    // ---- preload all per-row per-step data into LDS ----
    for (int i = tid; i < S_; i += 512) {
        const int tpc = topics[base + i];
        const int rsp = resps [base + i];
        sb_lds[i] = (tpc * 2 + rsp) * 512;
        qb_lds[i] = tpc * 32;
        sc_lds[i] = make_float4(tf_[base + i], af_[base + i], hf_[base + i],
                                masks[base + i] ? 1.f : 0.f);
    }

    // ---- f16-packed weights: own matrix full k=128 + gate k-slice ----
    const float* __restrict__ WpA =
        mat == 0 ? W_out :
        mat == 1 ? W_time + 129 * 128 :
        mat == 2 ? W_att  + 129 * 128 : W_hint + 129 * 128;
    uint32 Wn[64], Wg[16];
    #pragma unroll
    for (int i = 0; i < 64; ++i)
        Wn[i] = pack2(WpA[(2 * i) * 128 + u], WpA[(2 * i + 1) * 128 + u]);
    #pragma unroll
    for (int i = 0; i < 16; ++i)
        Wg[i] = pack2(W_gate[(mat * 32 + 2 * i) * 128 + u],
                      W_gate[(mat * 32 + 2 * i + 1) * 128 + u]);
    #pragma unroll
    for (int i = 0; i < 16; ++i) {
        asm volatile("" : "+v"(Wn[4*i]), "+v"(Wn[4*i+1]), "+v"(Wn[4*i+2]),
                          "+v"(Wn[4*i+3]), "+v"(Wg[i]));
    }

    // H[m][u] for m = mat*8 .. mat*8+7
    float H[8];
    #pragma unroll
    for (int j = 0; j < 8; ++j) H[j] = init_h[(mat * 8 + j) * 128 + u];

    // per-lane role constants
    const float cst_b  = (mat == 0 ? b_out : mat == 1 ? b_time :
                          mat == 2 ? b_att : b_hint)[u];
    const float cst_w0 = mat == 1 ? W_time[u] : mat == 2 ? W_att[u] :
                         mat == 3 ? W_hint[u] : 0.f;
    const float wl_own = mat == 1 ? w_lg[0] : mat == 2 ? w_lg[1] :
                         mat == 3 ? w_lg[2] : 0.f;
    const float bg = b_gate[u];
    const float wc0 = W_cap[0], wc1 = W_cap[1], wc2 = W_cap[2], wc3 = W_cap[3];
    const float wc4 = W_cap[4], wc5 = W_cap[5], wc6 = W_cap[6], wc7 = W_cap[7];
    const float bcap = b_cap[0];
    const int   svofs = (mat == 0 ? 384 : (mat - 1) * 128) + u;

    float* out_imp = out + B_ * (S_ - 1);

    __syncthreads();   // preload visible

    // ---- prime 2-deep pipelines ----
    float sv_cur = streams[sb_lds[0] + svofs];
    float sv_nxt = streams[sb_lds[1] + svofs];
    float qv_cur = 0.f;
    if (tid < 32) {
        w_lds[0][tid] = q_matrix[qb_lds[0] + tid];
        qv_cur        = q_matrix[qb_lds[1] + tid];   // row for step 1
    }
    __syncthreads();
    float4 wA = *(const float4*)&w_lds[0][mat * 8];
    float4 wB = *(const float4*)&w_lds[0][mat * 8 + 4];

    #pragma unroll 1
    for (int s = 0; s < S_; ++s) {
        const int buf = s & 1;

        // per-step scalars from LDS (broadcast), prefetch issue for s+2
        const float4 sc = sc_lds[s];
        const float tf = sc.x, af = sc.y, hf = sc.z, msk = sc.w;
        const int s2 = (s + 2 < S_) ? s + 2 : S_ - 1;
        const float sv_new = streams[sb_lds[s2] + svofs];
        float qv_new = 0.f;
        if (tid < 32) qv_new = q_matrix[qb_lds[s2] + tid];
        const float sv3b = __shfl(sv_cur, lane & ~3);   // gate stream val (lane0's)

        // ---- h_tilde partial + reduce over the 4 role lanes ----
        float hp = wA.x * H[0] + wA.y * H[1] + wA.z * H[2] + wA.w * H[3]
                 + wB.x * H[4] + wB.y * H[5] + wB.z * H[6] + wB.w * H[7];
        hp += __shfl_xor(hp, 1);
        hp += __shfl_xor(hp, 2);
        const float hp2 = __shfl_down(hp, 4);           // ht of unit u+1
        if (mat == 0 && !(u & 1)) ht_pk[buf][u >> 1] = pack2(hp, hp2);
        if (tid < 32) w_lds[buf ^ 1][tid] = qv_cur;     // w row for s+1
        LDS_BARRIER();

        // ---- deferred output flush: every 4 steps, 8 waves x 1 reduction ----
        if ((s & 3) == 0 && s) {
            const int st = (s - 4) + (wv >> 1);
            const int which = wv & 1;
            float v = outbuf[st & 7][2 * lane][which] +
                      outbuf[st & 7][2 * lane + 1][which];
            #pragma unroll
            for (int o = 1; o < 64; o <<= 1) v += __shfl_xor(v, o);
            if (lane == 0) {
                v *= (1.f / 128.f);
                if (which == 0) { if (st >= 1) out[b * (S_ - 1) + st - 1] = v; }
                else            out_imp[b * S_ + st] = v;
            }
        }

        const float4 wAn = *(const float4*)&w_lds[buf ^ 1][mat * 8];
        const float4 wBn = *(const float4*)&w_lds[buf ^ 1][mat * 8 + 4];

        // ---- own-matrix dot: full k=128, 4 parallel chains, no reduce ----
        const uint32* htb = &ht_pk[buf][0];
        float x0 = 0, x1 = 0, x2 = 0, x3 = 0;
        #pragma unroll
        for (int c = 0; c < 16; ++c) {
            const uint4 h4 = *(const uint4*)(htb + c * 4);
            x0 = dot2(Wn[c*4+0], h4.x, x0);
            x1 = dot2(Wn[c*4+1], h4.y, x1);
            x2 = dot2(Wn[c*4+2], h4.z, x2);
            x3 = dot2(Wn[c*4+3], h4.w, x3);
        }
        const float z = (x0 + x1) + (x2 + x3);

        // ---- gate dot: k-slice of 32, reduce over 4 lanes ----
        const uint32* htg = htb + mat * 16;
        float g0 = 0, g1 = 0, g2 = 0, g3 = 0;
        #pragma unroll
        for (int c = 0; c < 4; ++c) {
            const uint4 h4 = *(const uint4*)(htg + c * 4);
            g0 = dot2(Wg[c*4+0], h4.x, g0);
            g1 = dot2(Wg[c*4+1], h4.y, g1);
            g2 = dot2(Wg[c*4+2], h4.z, g2);
            g3 = dot2(Wg[c*4+3], h4.w, g3);
        }
        float z4 = (g0 + g1) + (g2 + g3);
        z4 += __shfl_xor(z4, 1);
        z4 += __shfl_xor(z4, 2);

        // ---- epilogue: roles in parallel lanes ----
        const float fac = mat == 1 ? tf : mat == 2 ? af : mat == 3 ? hf : 0.f;
        const float arg = z + (mat ? sv_cur : 0.f) + fac * cst_w0 + cst_b;
        const float g   = tanhf_(arg) * fac;
        float gs = wl_own * g;
        gs += __shfl_xor(gs, 1);
        gs += __shfl_xor(gs, 2);
        const float capin = wc0*tf + wc1*af + wc2*hf + wc3*(tf*af) + wc4*(tf*hf)
                          + wc5*(af*hf) + wc6*(tf*af*hf) + wc7 + bcap;
        const float cap   = sigmoidf_(capin);
        const float lg    = cap * fmaxf(gs, 0.f);
        const float gamma = sigmoidf_(z4 + sv3b + bg);

        const float gme = 1.f + msk * (gamma - 1.f);   // mask-folded
        const float lge = msk * lg;
        H[0] = fmaf(gme, H[0], wA.x * lge); H[1] = fmaf(gme, H[1], wA.y * lge);
        H[2] = fmaf(gme, H[2], wA.z * lge); H[3] = fmaf(gme, H[3], wA.w * lge);
        H[4] = fmaf(gme, H[4], wB.x * lge); H[5] = fmaf(gme, H[5], wB.y * lge);
        H[6] = fmaf(gme, H[6], wB.z * lge); H[7] = fmaf(gme, H[7], wB.w * lge);

        if (mat == 0) {
            const float sig = sigmoidf_(arg);          // arg = z0 + bo here
            float2 o2; o2.x = msk * sig; o2.y = lge;
            *(float2*)&outbuf[s & 7][u][0] = o2;
        }

        // rotate pipelines
        wA = wAn; wB = wBn;
        sv_cur = sv_nxt; sv_nxt = sv_new; qv_cur = qv_new;
    }

    // ---- final flush: steps 496..499 ----
    __syncthreads();
    {
        const int st = 496 + (wv >> 1);
        const int which = wv & 1;
        float v = outbuf[st & 7][2 * lane][which] +
                  outbuf[st & 7][2 * lane + 1][which];
        #pragma unroll
        for (int o = 1; o < 64; o <<= 1) v += __shfl_xor(v, o);
        if (lane == 0) {
            v *= (1.f / 128.f);
            if (which == 0) out[b * (S_ - 1) + st - 1] = v;
            else            out_imp[b * S_ + st] = v;
        }
    }
}

// ---------------------------------------------------------------------------
extern "C" void kernel_launch(void* const* d_in, const int* in_sizes, int n_in,
                              void* d_out, int out_size, void* d_ws, size_t ws_size,
                              hipStream_t stream)
{
    (void)in_sizes; (void)n_in; (void)out_size; (void)ws_size;

    const int*   topics    = (const int*)  d_in[0];
    const int*   resps     = (const int*)  d_in[1];
    const float* tf        = (const float*)d_in[2];
    const float* af        = (const float*)d_in[3];
    const float* hf        = (const float*)d_in[4];
    const int*   masks     = (const int*)  d_in[5];
    /* d_in[6] = training (ignored) */
    const float* emb_topic = (const float*)d_in[7];
    const float* emb_resps = (const float*)d_in[8];
    const float* q_matrix  = (const float*)d_in[9];
    const float* W_in      = (const float*)d_in[10];
    const float* b_in      = (const float*)d_in[11];
    const float* init_h    = (const float*)d_in[12];
    const float* W_out     = (const float*)d_in[13];
    const float* b_out     = (const float*)d_in[14];
    const float* W_time    = (const float*)d_in[15];
    const float* b_time    = (const float*)d_in[16];
    const float* W_att     = (const float*)d_in[17];
    const float* b_att     = (const float*)d_in[18];
    const float* W_hint    = (const float*)d_in[19];
    const float* b_hint    = (const float*)d_in[20];
    const float* W_cap     = (const float*)d_in[21];
    const float* b_cap     = (const float*)d_in[22];
    const float* w_lg      = (const float*)d_in[23];
    const float* W_gate    = (const float*)d_in[24];
    const float* b_gate    = (const float*)d_in[25];

    float* ws        = (float*)d_ws;
    float* topicAct  = ws;                         // 10000*128
    float* topicGate = topicAct + NT_ * 128;       // 10000*128
    float* respAct   = topicGate + NT_ * 128;      // 256
    float* streams   = respAct + 256;              // 10000*2*512

    prep_topic  <<<dim3(NT_ / 8 + 1, 2), 128, 0, stream>>>(
        emb_topic, emb_resps, W_in, W_gate, topicAct, topicGate, respAct);
    prep_streams<<<dim3(NT_ / 8, 4),     128, 0, stream>>>(
        topicAct, topicGate, respAct, b_in,
        W_time, W_att, W_hint, W_gate, streams);
    recurrent   <<<B_, 512, 0, stream>>>(topics, resps, tf, af, hf, masks,
                                         q_matrix, init_h,
                                         W_out, b_out, W_time, b_time,
                                         W_att, b_att, W_hint, b_hint,
                                         W_cap, b_cap, w_lg, W_gate, b_gate,
                                         streams, (float*)d_out);
}